// Round 10
// baseline (223.361 us; speedup 1.0000x reference)
//
#include <hip/hip_runtime.h>
#include <hip/hip_bf16.h>

#define DIMc 1024
#define Hc   16
#define DHc  64
#define Bc   4
#define Tc   1024

typedef __attribute__((ext_vector_type(8))) short s16x8;
typedef __attribute__((ext_vector_type(4))) short s16x4;
typedef __attribute__((ext_vector_type(4))) float f32x4;

__device__ inline short f2bf(float x) {
  unsigned u = __float_as_uint(x);
  u += 0x7fffu + ((u >> 16) & 1u);   // RNE
  return (short)(u >> 16);
}
__device__ inline float bf2f(short s) {
  return __uint_as_float(((unsigned)(unsigned short)s) << 16);
}
// packed f32x2 -> bf16x2 (RNE), single HW instr; no builtin on gfx950
__device__ inline unsigned cvtpk(float lo, float hi) {
  unsigned r;
  asm("v_cvt_pk_bf16_f32 %0, %1, %2" : "=v"(r) : "v"(lo), "v"(hi));
  return r;
}

#define MFMA16(a, b, c) __builtin_amdgcn_mfma_f32_16x16x32_bf16((a), (b), (c), 0, 0, 0)

// async global->LDS, 16B per lane; LDS dest = wave-uniform base + lane*16
__device__ __forceinline__ void gl16(const short* g, short* l) {
  __builtin_amdgcn_global_load_lds(
      (const __attribute__((address_space(1))) unsigned int*)g,
      (__attribute__((address_space(3))) unsigned int*)l, 16, 0, 0);
}

// ---------------------------------------------------------------------------
// casts
// ---------------------------------------------------------------------------
__global__ __launch_bounds__(256) void cast_f32_bf16(const float* __restrict__ in,
                                                     short* __restrict__ out, int n) {
  const int i = (blockIdx.x * 256 + threadIdx.x) * 8;
  if (i >= n) return;
  const float4 a = *(const float4*)(in + i);
  const float4 b = *(const float4*)(in + i + 4);
  s16x8 r;
  r[0] = f2bf(a.x); r[1] = f2bf(a.y); r[2] = f2bf(a.z); r[3] = f2bf(a.w);
  r[4] = f2bf(b.x); r[5] = f2bf(b.y); r[6] = f2bf(b.z); r[7] = f2bf(b.w);
  *(s16x8*)(out + i) = r;
}

__global__ __launch_bounds__(256) void cast6_f32_bf16(
    const float* s0, const float* s1, const float* s2, const float* s3,
    const float* s4, const float* s5,
    short* d0, short* d1, short* d2, short* d3, short* d4, short* d5) {
  const float* sp[6] = {s0, s1, s2, s3, s4, s5};
  short* dp[6] = {d0, d1, d2, d3, d4, d5};
  const int z = blockIdx.z;
  const float* in = sp[z];
  short* out = dp[z];
  const int i = (blockIdx.x * 256 + threadIdx.x) * 8;
  const float4 a = *(const float4*)(in + i);
  const float4 b = *(const float4*)(in + i + 4);
  s16x8 r;
  r[0] = f2bf(a.x); r[1] = f2bf(a.y); r[2] = f2bf(a.z); r[3] = f2bf(a.w);
  r[4] = f2bf(b.x); r[5] = f2bf(b.y); r[6] = f2bf(b.z); r[7] = f2bf(b.w);
  *(s16x8*)(out + i) = r;
}

// ---------------------------------------------------------------------------
// m97-style GEMM core: 128x128 tile, BK=32, K=1024, ld=1024 (B^T form),
// global_load_lds w16 staging, double-buffered linear LDS [128][32],
// chunk swizzle: LDS[row][kq] = G[row][kq ^ (row&3)]; read chunk = lg^(ll&3).
// One barrier per K-step. Ends with a barrier -> LDS reusable after return.
// ---------------------------------------------------------------------------
__device__ __forceinline__ void gemm_core(const short* __restrict__ Ab,
                                          const short* __restrict__ Bb,
                                          int bm, int bn,
                                          short (*As)[4096], short (*Bs)[4096],
                                          f32x4 (&acc)[4][4]) {
  const int tid = threadIdx.x;
  const int w = tid >> 6, l = tid & 63;
  const int wr = w >> 1, wc = w & 1;
  const int ll = l & 15, lg = l >> 4;

  // staging geometry: chunk c = w*128 + j*64 + l ; row=c>>2 ; kq=c&3
  const int r0 = (w * 128 + l) >> 2;           // j=0 row (j=1: +16)
  const int ksw = ((l & 3) ^ ((l >> 2) & 3)) * 8;  // swizzled source chunk
  const short* pA0 = Ab + (size_t)(bm + r0) * 1024 + ksw;
  const short* pA1 = Ab + (size_t)(bm + r0 + 16) * 1024 + ksw;
  const short* pB0 = Bb + (size_t)(bn + r0) * 1024 + ksw;
  const short* pB1 = Bb + (size_t)(bn + r0 + 16) * 1024 + ksw;
  const int lb = w * 1024;                     // wave's LDS segment (shorts)

  gl16(pA0, &As[0][lb]);
  gl16(pA1, &As[0][lb + 512]);
  gl16(pB0, &Bs[0][lb]);
  gl16(pB1, &Bs[0][lb + 512]);
  __syncthreads();

  const int kcA = ((lg ^ (ll & 3)) * 8);
  int cur = 0;
  for (int k0 = 0; k0 < 1024; k0 += 32) {
    if (k0 + 32 < 1024) {
      const int nx = cur ^ 1;
      gl16(pA0 + k0 + 32, &As[nx][lb]);
      gl16(pA1 + k0 + 32, &As[nx][lb + 512]);
      gl16(pB0 + k0 + 32, &Bs[nx][lb]);
      gl16(pB1 + k0 + 32, &Bs[nx][lb + 512]);
    }
    s16x8 af[4], bf_[4];
#pragma unroll
    for (int i = 0; i < 4; ++i) {
      af[i]  = *(const s16x8*)&As[cur][(wr * 64 + i * 16 + ll) * 32 + kcA];
      bf_[i] = *(const s16x8*)&Bs[cur][(wc * 64 + i * 16 + ll) * 32 + kcA];
    }
    __builtin_amdgcn_s_setprio(1);
#pragma unroll
    for (int mi = 0; mi < 4; ++mi)
#pragma unroll
      for (int ni = 0; ni < 4; ++ni)
        acc[mi][ni] = MFMA16(af[mi], bf_[ni], acc[mi][ni]);
    __builtin_amdgcn_s_setprio(0);
    __syncthreads();   // drains prefetch vmcnt + all lgkm; buffers swap safely
    cur ^= 1;
  }
}

// ---------------------------------------------------------------------------
// Unified projection: z=0 Q (dual out), z=1 K, z=2 V^T (via LDS transpose),
// z=3 P2 table.
// V^T layout: Vw[((b*H+h)*64+dh)*1024 + t]  (d-major, t contiguous)
// ---------------------------------------------------------------------------
__global__ __launch_bounds__(256) void proj_all(
    const short* __restrict__ xb, const short* __restrict__ pb,
    const short* __restrict__ Wqb, const short* __restrict__ Wkb,
    const short* __restrict__ Wvb, const short* __restrict__ Wpb,
    const float* __restrict__ bq, const float* __restrict__ bk,
    const float* __restrict__ bv,
    const float* __restrict__ pbu, const float* __restrict__ pbv,
    short* __restrict__ Quw, short* __restrict__ Qvw,
    short* __restrict__ Kw, short* __restrict__ Vw,
    short* __restrict__ P2o) {
  const int z = blockIdx.z;
  if (z == 3 && blockIdx.x >= 8) return;   // P2: M=1024 only (uniform exit)
  __shared__ __align__(16) short LDSu[17408];   // As|Bs (16384) / T (128x136)
  short (*As)[4096] = (short (*)[4096])(LDSu);
  short (*Bs)[4096] = (short (*)[4096])(LDSu + 8192);

  const short* Ab = (z == 3) ? pb : xb;
  const short* Bb = (z == 0) ? Wqb : (z == 1) ? Wkb : (z == 2) ? Wvb : Wpb;

  f32x4 acc[4][4];
#pragma unroll
  for (int i = 0; i < 4; ++i)
#pragma unroll
    for (int j = 0; j < 4; ++j) acc[i][j] = (f32x4){0.f, 0.f, 0.f, 0.f};

  const int bm = blockIdx.x * 128, bn = blockIdx.y * 128;
  gemm_core(Ab, Bb, bm, bn, As, Bs, acc);

  const int tid = threadIdx.x;
  const int w = tid >> 6, l = tid & 63;
  const int wr = w >> 1, wc = w & 1;
  const int ll = l & 15, lg = l >> 4;

  if (z == 2) {
    // ---- V^T epilogue: frag -> LDS (col-major, stride 136) -> coalesced ----
    short* T = LDSu;
#pragma unroll
    for (int mi = 0; mi < 4; ++mi)
#pragma unroll
      for (int ni = 0; ni < 4; ++ni) {
        const int col = wc * 64 + ni * 16 + ll;
        const int row0 = wr * 64 + mi * 16 + lg * 4;
        const float bias = bv[bn + col];
        s16x4 t4;
#pragma unroll
        for (int r = 0; r < 4; ++r) t4[r] = f2bf(acc[mi][ni][r] + bias);
        *(s16x4*)&T[col * 136 + row0] = t4;
      }
    __syncthreads();
    const int b_ = bm >> 10;
    const int t0 = bm & 1023;
#pragma unroll
    for (int i = 0; i < 4; ++i) {
      const int c2 = tid + i * 256;            // 1024 units
      const int colL = c2 >> 3;                // 0..127
      const int rb = (c2 & 7) * 16;            // 0..112
      const s16x8 v0 = *(const s16x8*)&T[colL * 136 + rb];
      const s16x8 v1 = *(const s16x8*)&T[colL * 136 + rb + 8];
      const int gcol = bn + colL;
      const int hh = gcol >> 6, dh = gcol & 63;
      short* dst = Vw + (((size_t)b_ * Hc + hh) * DHc + dh) * Tc + t0 + rb;
      *(s16x8*)dst = v0;
      *(s16x8*)(dst + 8) = v1;
    }
    return;
  }

#pragma unroll
  for (int mi = 0; mi < 4; ++mi)
#pragma unroll
    for (int ni = 0; ni < 4; ++ni)
#pragma unroll
      for (int r = 0; r < 4; ++r) {
        const int row = bm + wr * 64 + mi * 16 + lg * 4 + r;
        const int col = bn + wc * 64 + ni * 16 + ll;
        float v = acc[mi][ni][r];
        if (z == 3) {
          // P2[h][t]=p[t]; P2[h][1024]=0; P2[h][1025+t]=p[t] (t<=1021); P2[h][2047]=0
          const int hh = col >> 6, dh = col & 63;
          const short v16 = f2bf(v);
          short* P2h = P2o + ((size_t)hh * 2048) * DHc;
          P2h[(size_t)row * DHc + dh] = v16;
          if (row <= 1021) P2h[(size_t)(1025 + row) * DHc + dh] = v16;
          if (row == 1023) P2h[(size_t)1024 * DHc + dh] = 0;
          if (row == 1022) P2h[(size_t)2047 * DHc + dh] = 0;
        } else {
          const int b_ = row >> 10, t = row & 1023, hh = col >> 6, dh = col & 63;
          const size_t o = (((size_t)b_ * Hc + hh) * Tc + t) * DHc + dh;
          if (z == 0) {
            v += bq[col];
            Quw[o] = f2bf((v + pbu[col]) * 0.125f);
            Qvw[o] = f2bf((v + pbv[col]) * 0.125f);
          } else {
            Kw[o] = f2bf(v + bk[col]);
          }
        }
      }
}

// ---------------------------------------------------------------------------
// Output projection (f32 out + bias)
// ---------------------------------------------------------------------------
__global__ __launch_bounds__(256) void wo_gemm(const short* __restrict__ A,
                                               const short* __restrict__ B,
                                               const float* __restrict__ bias,
                                               float* __restrict__ Cf) {
  __shared__ __align__(16) short As[2][4096];
  __shared__ __align__(16) short Bs[2][4096];
  f32x4 acc[4][4];
#pragma unroll
  for (int i = 0; i < 4; ++i)
#pragma unroll
    for (int j = 0; j < 4; ++j) acc[i][j] = (f32x4){0.f, 0.f, 0.f, 0.f};

  const int bm = blockIdx.x * 128, bn = blockIdx.y * 128;
  gemm_core(A, B, bm, bn, As, Bs, acc);

  const int tid = threadIdx.x;
  const int w = tid >> 6, l = tid & 63;
  const int wr = w >> 1, wc = w & 1;
  const int ll = l & 15, lg = l >> 4;
#pragma unroll
  for (int mi = 0; mi < 4; ++mi)
#pragma unroll
    for (int ni = 0; ni < 4; ++ni)
#pragma unroll
      for (int r = 0; r < 4; ++r) {
        const int row = bm + wr * 64 + mi * 16 + lg * 4 + r;
        const int col = bn + wc * 64 + ni * 16 + ll;
        Cf[(size_t)row * DIMc + col] = acc[mi][ni][r] + bias[col];
      }
}

// ---------------------------------------------------------------------------
// Flash attention -- ROUND-8 softmax/math byte-identical (known good), with
// ONE change (bisect): pos B-frags read DIRECTLY from global P2 (L2-resident
// per-head; drop the P2w LDS stage) -> LDS 48.4 -> 29.3 KB, VGPR down, 4
// blocks/CU naturally.
//   dq<=0 -> qv[q]  .P2[dq+1023]   (diag pass)
//   dq>=1 -> qv[q+1].P2[dq+1023]   (upper pass; P2[1024]=0 covers dq==1)
// ---------------------------------------------------------------------------
__global__ __launch_bounds__(256) void flash_attn(
    const short* __restrict__ Qu, const short* __restrict__ Qv,
    const short* __restrict__ Kg, const short* __restrict__ VTg,
    const short* __restrict__ P2, short* __restrict__ ctx) {
  __shared__ __align__(16) short L[14976];   // 29.3 KB
  short* Kt  = L;            // [key(64)][72]
  short* Vt  = L + 4608;     // [d(64)][key(64)^swz] stride 72
  short* U   = L + 9216;     // [4 waves][1440]: SPW(80x18) / P-tile(16x72)

  const int tid = threadIdx.x;
  const int w = tid >> 6, l = tid & 63;
  const int ll = l & 15, lg = l >> 4;
  // XCD swizzle (bijective: 1024 = 8 * 128)
  const int orig = blockIdx.x + (blockIdx.y << 4) + (blockIdx.z << 8);
  const int wg = (orig & 7) * 128 + (orig >> 3);
  const int qt = wg & 15, h = (wg >> 4) & 15, b = wg >> 8;
  const int q0 = qt * 64;

  const size_t bh = (size_t)b * Hc + h;
  const short* Qup = Qu + (bh * Tc + q0) * DHc;
  const short* Qvp = Qv + (bh * Tc + q0) * DHc;
  const short* Kgp = Kg + bh * Tc * DHc;
  const short* VTp = VTg + bh * DHc * Tc;
  const short* P2h = P2 + (size_t)h * 2048 * DHc;

  // ---- Q fragments straight from global (once per block) ----
  s16x8 qau[2], qav[2], qav1[2];
  {
    const short* qr  = Qup + (size_t)(w * 16 + ll) * 64;
    const short* qvr = Qvp + (size_t)(w * 16 + ll) * 64;
#pragma unroll
    for (int ks = 0; ks < 2; ++ks) {
      qau[ks]  = *(const s16x8*)(qr + ks * 32 + lg * 8);
      qav[ks]  = *(const s16x8*)(qvr + ks * 32 + lg * 8);
      // row+1 for the upper pass; qt==15 tail overread stays inside d_ws and
      // feeds only never-gathered cells (q=1023 has no dq>=1 keys).
      qav1[ks] = *(const s16x8*)(qvr + 64 + ks * 32 + lg * 8);
    }
  }

  f32x4 o[4];
#pragma unroll
  for (int cd = 0; cd < 4; ++cd) o[cd] = (f32x4){0.f, 0.f, 0.f, 0.f};
  float m_run[4], l_run[4];
#pragma unroll
  for (int r = 0; r < 4; ++r) { m_run[r] = -3.0e38f; l_run[r] = 0.f; }

  const int ci2lo = 3 - w;       // wave's first pos-frag in window space
  const int spwb = w * 1440;     // wave's U base

  // T14 pipeline registers (K/V loads for tile kt+1 in flight during tile kt)
  s16x8 kr[2], vr[2];
  auto issue = [&](int kt) {
#pragma unroll
    for (int i = 0; i < 2; ++i) {
      const int c = tid + i * 256;
      const int row = c >> 3, col8 = (c & 7) * 8;
      kr[i] = *(const s16x8*)(Kgp + (size_t)(kt * 64 + row) * 64 + col8);
      vr[i] = *(const s16x8*)(VTp + (size_t)row * Tc + kt * 64 + col8);
    }
  };
  issue(0);

  for (int kt = 0; kt < 16; ++kt) {
    const int dtile = kt - qt;
    const int wbase = dtile * 64 + 960;   // in [0, 1920]
    __syncthreads();  // A: all prior-iter LDS reads complete
#pragma unroll
    for (int i = 0; i < 2; ++i) {
      const int c = tid + i * 256;
      const int row = c >> 3, col8 = (c & 7) * 8;
      *(s16x8*)&Kt[row * 72 + col8] = kr[i];
      // V^T staging: same key-chunk XOR swizzle the read path expects
      *(s16x8*)&Vt[row * 72 + (col8 ^ (((row >> 3) & 3) << 3))] = vr[i];
    }
    __syncthreads();  // B: staging visible
    if (kt < 15) issue(kt + 1);   // next tile's loads fly under this compute

    // ---- QK^T ----
    f32x4 s[4];
#pragma unroll
    for (int ci = 0; ci < 4; ++ci) s[ci] = (f32x4){0.f, 0.f, 0.f, 0.f};
#pragma unroll
    for (int ks = 0; ks < 2; ++ks) {
      s16x8 kb[4];
#pragma unroll
      for (int ci = 0; ci < 4; ++ci)
        kb[ci] = *(const s16x8*)&Kt[(ci * 16 + ll) * 72 + ks * 32 + lg * 8];
      __builtin_amdgcn_s_setprio(1);
#pragma unroll
      for (int ci = 0; ci < 4; ++ci) s[ci] = MFMA16(qau[ks], kb[ci], s[ci]);
      __builtin_amdgcn_s_setprio(0);
    }

    // ---- pos-score windows (two passes sharing U's SPW view) ----
    if (dtile <= 0) {   // diag: A = qv[q], cells dq <= 0
      f32x4 pc[5];
#pragma unroll
      for (int j = 0; j < 5; ++j) pc[j] = (f32x4){0.f, 0.f, 0.f, 0.f};
#pragma unroll
      for (int ks = 0; ks < 2; ++ks) {
        s16x8 pb[5];
#pragma unroll
        for (int j = 0; j < 5; ++j)
          pb[j] = *(const s16x8*)(P2h +
                  (size_t)(wbase + (ci2lo + j) * 16 + ll) * 64 + ks * 32 + lg * 8);
        __builtin_amdgcn_s_setprio(1);
#pragma unroll
        for (int j = 0; j < 5; ++j) pc[j] = MFMA16(qav[ks], pb[j], pc[j]);
        __builtin_amdgcn_s_setprio(0);
      }
#pragma unroll
      for (int j = 0; j < 5; ++j) {
        const int ba = spwb + (j * 16 + ll) * 18 + lg * 4;
        *(unsigned*)&U[ba]     = cvtpk(pc[j][0], pc[j][1]);
        *(unsigned*)&U[ba + 2] = cvtpk(pc[j][2], pc[j][3]);
      }
      asm volatile("s_waitcnt lgkmcnt(0)" ::: "memory");
#pragma unroll
      for (int ci = 0; ci < 4; ++ci)
#pragma unroll
        for (int r = 0; r < 4; ++r) {
          const int rel = ci * 16 + ll - w * 16 - lg * 4 - r;  // dq - dtile*64
          if (dtile < 0 || rel <= 0)
            s[ci][r] += bf2f(U[spwb + (rel + w * 16 + 15) * 18 + lg * 4 + r]);
        }
      asm volatile("s_waitcnt lgkmcnt(0)" ::: "memory");  // reads before reuse
    }
    if (dtile >= 0) {   // upper: A = qv[q+1], cells dq >= 1
      f32x4 pc[5];
#pragma unroll
      for (int j = 0; j < 5; ++j) pc[j] = (f32x4){0.f, 0.f, 0.f, 0.f};
#pragma unroll
      for (int ks = 0; ks < 2; ++ks) {
        s16x8 pb[5];
#pragma unroll
        for (int j = 0; j < 5; ++j)
          pb[j] = *(const s16x8*)(P2h +
                  (size_t)(wbase + (ci2lo + j) * 16 + ll) * 64 + ks * 32 + lg * 8);
        __builtin_amdgcn_s_setprio(1);
#pragma unroll
        for (int j = 0; j < 5; ++j) pc[j] = MFMA16(qav1[ks], pb[j], pc[j]);
        __builtin_amdgcn_s_setprio(0);
      }
#pragma unroll
      for (int j = 0; j < 5; ++j) {
        const int ba = spwb + (j * 16 + ll) * 18 + lg * 4;
        *(unsigned*)&U[ba]     = cvtpk(pc[j][0], pc[j][1]);
        *(unsigned*)&U[ba + 2] = cvtpk(pc[j][2], pc[j][3]);
      }
      asm volatile("s_waitcnt lgkmcnt(0)" ::: "memory");
#pragma unroll
      for (int ci = 0; ci < 4; ++ci)
#pragma unroll
        for (int r = 0; r < 4; ++r) {
          const int rel = ci * 16 + ll - w * 16 - lg * 4 - r;
          if (dtile > 0 || rel >= 1)
            s[ci][r] += bf2f(U[spwb + (rel + w * 16 + 15) * 18 + lg * 4 + r]);
        }
      asm volatile("s_waitcnt lgkmcnt(0)" ::: "memory");
    }

    // ---- online softmax (rows in 16-lane groups) -- round-8 exact ----
    float fac[4];
#pragma unroll
    for (int r = 0; r < 4; ++r) {
      float mx = fmaxf(fmaxf(s[0][r], s[1][r]), fmaxf(s[2][r], s[3][r]));
      mx = fmaxf(mx, __shfl_xor(mx, 1));
      mx = fmaxf(mx, __shfl_xor(mx, 2));
      mx = fmaxf(mx, __shfl_xor(mx, 4));
      mx = fmaxf(mx, __shfl_xor(mx, 8));
      const float mnew = fmaxf(m_run[r], mx);
      const float f = __expf(m_run[r] - mnew);
      float lsum = 0.f;
#pragma unroll
      for (int ci = 0; ci < 4; ++ci) {
        const float e = __expf(s[ci][r] - mnew);
        s[ci][r] = e;
        lsum += e;
      }
      lsum += __shfl_xor(lsum, 1);
      lsum += __shfl_xor(lsum, 2);
      lsum += __shfl_xor(lsum, 4);
      lsum += __shfl_xor(lsum, 8);
      m_run[r] = mnew;
      l_run[r] = l_run[r] * f + lsum;
      fac[r] = f;
    }
#pragma unroll
    for (int cd = 0; cd < 4; ++cd)
#pragma unroll
      for (int r = 0; r < 4; ++r) o[cd][r] *= fac[r];

    // ---- P -> U (wave-private P-tile rows, stride 72; cvt_pk pairs) ----
#pragma unroll
    for (int ci = 0; ci < 4; ++ci) {
      const unsigned p01 = cvtpk(s[ci][0], s[ci][1]);
      const unsigned p23 = cvtpk(s[ci][2], s[ci][3]);
      const int base = spwb + lg * 4 * 72 + ci * 16 + ll;
      U[base]           = (short)p01;
      U[base + 72]      = (short)(p01 >> 16);
      U[base + 144]     = (short)p23;
      U[base + 216]     = (short)(p23 >> 16);
    }
    asm volatile("s_waitcnt lgkmcnt(0)" ::: "memory");

    // ---- PV ----
#pragma unroll
    for (int ks = 0; ks < 2; ++ks) {
      s16x8 pa = *(const s16x8*)&U[spwb + ll * 72 + ks * 32 + lg * 8];
      s16x8 vv[4];
#pragma unroll
      for (int cd = 0; cd < 4; ++cd) {
        const int d = cd * 16 + ll;
        const int key8 = ks * 32 + lg * 8;
        vv[cd] = *(const s16x8*)&Vt[d * 72 + (key8 ^ (((d >> 3) & 3) << 3))];
      }
      __builtin_amdgcn_s_setprio(1);
#pragma unroll
      for (int cd = 0; cd < 4; ++cd) o[cd] = MFMA16(pa, vv[cd], o[cd]);
      __builtin_amdgcn_s_setprio(0);
    }
  }

  // ---- finalize ----
#pragma unroll
  for (int r = 0; r < 4; ++r) {
    const float inv = 1.f / l_run[r];
    const int row = q0 + w * 16 + lg * 4 + r;
#pragma unroll
    for (int cd = 0; cd < 4; ++cd) {
      const int d = cd * 16 + ll;
      ctx[((size_t)b * Tc + row) * DIMc + h * DHc + d] = f2bf(o[cd][r] * inv);
    }
  }
}

// ---------------------------------------------------------------------------
extern "C" void kernel_launch(void* const* d_in, const int* in_sizes, int n_in,
                              void* d_out, int out_size, void* d_ws,
                              size_t ws_size, hipStream_t stream) {
  const float* x   = (const float*)d_in[0];
  const float* pos = (const float*)d_in[1];
  // d_in[2] = mask (all-True, unused)
  const float* Wq  = (const float*)d_in[3];
  const float* bq  = (const float*)d_in[4];
  const float* Wk  = (const float*)d_in[5];
  const float* bk  = (const float*)d_in[6];
  const float* Wv  = (const float*)d_in[7];
  const float* bv  = (const float*)d_in[8];
  const float* Wp  = (const float*)d_in[9];
  const float* Wo  = (const float*)d_in[10];
  const float* bo  = (const float*)d_in[11];
  const float* pbu = (const float*)d_in[12];
  const float* pbv = (const float*)d_in[13];
  float* out = (float*)d_out;

  char* ws = (char*)d_ws;
  const size_t MB = 1024 * 1024;
  short* xb  = (short*)(ws + 0 * MB);    // x bf16                 8 MB
  short* pb  = (short*)(ws + 8 * MB);    // pos bf16               2 MB
  short* Wqb = (short*)(ws + 10 * MB);
  short* Wkb = (short*)(ws + 12 * MB);
  short* Wvb = (short*)(ws + 14 * MB);
  short* Wpb = (short*)(ws + 16 * MB);
  short* Wob = (short*)(ws + 18 * MB);
  short* Quw = (short*)(ws + 20 * MB);   // (q+bq+pbu)/8 head-split 8 MB
  short* Qvw = (short*)(ws + 28 * MB);   // (q+bq+pbv)/8 head-split 8 MB
  short* Kw  = (short*)(ws + 36 * MB);   // [b,h,t,64]              8 MB
  short* Vw  = (short*)(ws + 44 * MB);   // V^T [b,h,64,t]          8 MB
  short* P2w_ = (short*)(ws + 52 * MB);  // P2 [h][2048][64]        4 MB
  short* Cw  = (short*)(ws + 56 * MB);   // ctx bf16 [b,t,1024]     8 MB

  const dim3 blk(256);
  hipLaunchKernelGGL(cast_f32_bf16, dim3(2048), blk, 0, stream, x, xb, 4194304);
  hipLaunchKernelGGL(cast6_f32_bf16, dim3(512, 1, 6), blk, 0, stream,
                     pos, Wq, Wk, Wv, Wp, Wo, pb, Wqb, Wkb, Wvb, Wpb, Wob);

  // Q/K/V projections + P2 table in one launch (z = 0..3)
  hipLaunchKernelGGL(proj_all, dim3(32, 8, 4), blk, 0, stream,
                     xb, pb, Wqb, Wkb, Wvb, Wpb, bq, bk, bv, pbu, pbv,
                     Quw, Qvw, Kw, Vw, P2w_);
  // fused flash attention (single launch, all batches)
  hipLaunchKernelGGL(flash_attn, dim3(16, 16, 4), blk, 0, stream,
                     Quw, Qvw, Kw, Vw, P2w_, Cw);
  // output projection (f32 out)
  hipLaunchKernelGGL(wo_gemm, dim3(32, 8), blk, 0, stream, Cw, Wob, bo, out);
}

// Round 11
// 193.719 us; speedup vs baseline: 1.1530x; 1.1530x over previous
//
#include <hip/hip_runtime.h>
#include <hip/hip_bf16.h>

#define DIMc 1024
#define Hc   16
#define DHc  64
#define Bc   4
#define Tc   1024

typedef __attribute__((ext_vector_type(8))) short s16x8;
typedef __attribute__((ext_vector_type(4))) short s16x4;
typedef __attribute__((ext_vector_type(4))) float f32x4;

__device__ inline short f2bf(float x) {
  unsigned u = __float_as_uint(x);
  u += 0x7fffu + ((u >> 16) & 1u);   // RNE
  return (short)(u >> 16);
}
__device__ inline float bf2f(short s) {
  return __uint_as_float(((unsigned)(unsigned short)s) << 16);
}
// packed f32x2 -> bf16x2 (RNE), single HW instr; no builtin on gfx950
__device__ inline unsigned cvtpk(float lo, float hi) {
  unsigned r;
  asm("v_cvt_pk_bf16_f32 %0, %1, %2" : "=v"(r) : "v"(lo), "v"(hi));
  return r;
}

#define MFMA16(a, b, c) __builtin_amdgcn_mfma_f32_16x16x32_bf16((a), (b), (c), 0, 0, 0)

// async global->LDS, 16B per lane; LDS dest = wave-uniform base + lane*16
__device__ __forceinline__ void gl16(const short* g, short* l) {
  __builtin_amdgcn_global_load_lds(
      (const __attribute__((address_space(1))) unsigned int*)g,
      (__attribute__((address_space(3))) unsigned int*)l, 16, 0, 0);
}

// ---------------------------------------------------------------------------
// casts
// ---------------------------------------------------------------------------
__global__ __launch_bounds__(256) void cast_f32_bf16(const float* __restrict__ in,
                                                     short* __restrict__ out, int n) {
  const int i = (blockIdx.x * 256 + threadIdx.x) * 8;
  if (i >= n) return;
  const float4 a = *(const float4*)(in + i);
  const float4 b = *(const float4*)(in + i + 4);
  s16x8 r;
  r[0] = f2bf(a.x); r[1] = f2bf(a.y); r[2] = f2bf(a.z); r[3] = f2bf(a.w);
  r[4] = f2bf(b.x); r[5] = f2bf(b.y); r[6] = f2bf(b.z); r[7] = f2bf(b.w);
  *(s16x8*)(out + i) = r;
}

__global__ __launch_bounds__(256) void cast6_f32_bf16(
    const float* s0, const float* s1, const float* s2, const float* s3,
    const float* s4, const float* s5,
    short* d0, short* d1, short* d2, short* d3, short* d4, short* d5) {
  const float* sp[6] = {s0, s1, s2, s3, s4, s5};
  short* dp[6] = {d0, d1, d2, d3, d4, d5};
  const int z = blockIdx.z;
  const float* in = sp[z];
  short* out = dp[z];
  const int i = (blockIdx.x * 256 + threadIdx.x) * 8;
  const float4 a = *(const float4*)(in + i);
  const float4 b = *(const float4*)(in + i + 4);
  s16x8 r;
  r[0] = f2bf(a.x); r[1] = f2bf(a.y); r[2] = f2bf(a.z); r[3] = f2bf(a.w);
  r[4] = f2bf(b.x); r[5] = f2bf(b.y); r[6] = f2bf(b.z); r[7] = f2bf(b.w);
  *(s16x8*)(out + i) = r;
}

// ---------------------------------------------------------------------------
// m97-style GEMM core: 128x128 tile, BK=32, K=1024, ld=1024 (B^T form),
// global_load_lds w16 staging, double-buffered linear LDS [128][32],
// chunk swizzle: LDS[row][kq] = G[row][kq ^ (row&3)]; read chunk = lg^(ll&3).
// One barrier per K-step. Ends with a barrier -> LDS reusable after return.
// ---------------------------------------------------------------------------
__device__ __forceinline__ void gemm_core(const short* __restrict__ Ab,
                                          const short* __restrict__ Bb,
                                          int bm, int bn,
                                          short (*As)[4096], short (*Bs)[4096],
                                          f32x4 (&acc)[4][4]) {
  const int tid = threadIdx.x;
  const int w = tid >> 6, l = tid & 63;
  const int wr = w >> 1, wc = w & 1;
  const int ll = l & 15, lg = l >> 4;

  // staging geometry: chunk c = w*128 + j*64 + l ; row=c>>2 ; kq=c&3
  const int r0 = (w * 128 + l) >> 2;           // j=0 row (j=1: +16)
  const int ksw = ((l & 3) ^ ((l >> 2) & 3)) * 8;  // swizzled source chunk
  const short* pA0 = Ab + (size_t)(bm + r0) * 1024 + ksw;
  const short* pA1 = Ab + (size_t)(bm + r0 + 16) * 1024 + ksw;
  const short* pB0 = Bb + (size_t)(bn + r0) * 1024 + ksw;
  const short* pB1 = Bb + (size_t)(bn + r0 + 16) * 1024 + ksw;
  const int lb = w * 1024;                     // wave's LDS segment (shorts)

  gl16(pA0, &As[0][lb]);
  gl16(pA1, &As[0][lb + 512]);
  gl16(pB0, &Bs[0][lb]);
  gl16(pB1, &Bs[0][lb + 512]);
  __syncthreads();

  const int kcA = ((lg ^ (ll & 3)) * 8);
  int cur = 0;
  for (int k0 = 0; k0 < 1024; k0 += 32) {
    if (k0 + 32 < 1024) {
      const int nx = cur ^ 1;
      gl16(pA0 + k0 + 32, &As[nx][lb]);
      gl16(pA1 + k0 + 32, &As[nx][lb + 512]);
      gl16(pB0 + k0 + 32, &Bs[nx][lb]);
      gl16(pB1 + k0 + 32, &Bs[nx][lb + 512]);
    }
    s16x8 af[4], bf_[4];
#pragma unroll
    for (int i = 0; i < 4; ++i) {
      af[i]  = *(const s16x8*)&As[cur][(wr * 64 + i * 16 + ll) * 32 + kcA];
      bf_[i] = *(const s16x8*)&Bs[cur][(wc * 64 + i * 16 + ll) * 32 + kcA];
    }
    __builtin_amdgcn_s_setprio(1);
#pragma unroll
    for (int mi = 0; mi < 4; ++mi)
#pragma unroll
      for (int ni = 0; ni < 4; ++ni)
        acc[mi][ni] = MFMA16(af[mi], bf_[ni], acc[mi][ni]);
    __builtin_amdgcn_s_setprio(0);
    __syncthreads();   // drains prefetch vmcnt + all lgkm; buffers swap safely
    cur ^= 1;
  }
}

// ---------------------------------------------------------------------------
// Unified projection: z=0 Q (dual out), z=1 K, z=2 V^T (via LDS transpose),
// z=3 P2 table.
// V^T layout: Vw[((b*H+h)*64+dh)*1024 + t]  (d-major, t contiguous)
// ---------------------------------------------------------------------------
__global__ __launch_bounds__(256) void proj_all(
    const short* __restrict__ xb, const short* __restrict__ pb,
    const short* __restrict__ Wqb, const short* __restrict__ Wkb,
    const short* __restrict__ Wvb, const short* __restrict__ Wpb,
    const float* __restrict__ bq, const float* __restrict__ bk,
    const float* __restrict__ bv,
    const float* __restrict__ pbu, const float* __restrict__ pbv,
    short* __restrict__ Quw, short* __restrict__ Qvw,
    short* __restrict__ Kw, short* __restrict__ Vw,
    short* __restrict__ P2o) {
  const int z = blockIdx.z;
  if (z == 3 && blockIdx.x >= 8) return;   // P2: M=1024 only (uniform exit)
  __shared__ __align__(16) short LDSu[17408];   // As|Bs (16384) / T (128x136)
  short (*As)[4096] = (short (*)[4096])(LDSu);
  short (*Bs)[4096] = (short (*)[4096])(LDSu + 8192);

  const short* Ab = (z == 3) ? pb : xb;
  const short* Bb = (z == 0) ? Wqb : (z == 1) ? Wkb : (z == 2) ? Wvb : Wpb;

  f32x4 acc[4][4];
#pragma unroll
  for (int i = 0; i < 4; ++i)
#pragma unroll
    for (int j = 0; j < 4; ++j) acc[i][j] = (f32x4){0.f, 0.f, 0.f, 0.f};

  const int bm = blockIdx.x * 128, bn = blockIdx.y * 128;
  gemm_core(Ab, Bb, bm, bn, As, Bs, acc);

  const int tid = threadIdx.x;
  const int w = tid >> 6, l = tid & 63;
  const int wr = w >> 1, wc = w & 1;
  const int ll = l & 15, lg = l >> 4;

  if (z == 2) {
    // ---- V^T epilogue: frag -> LDS (col-major, stride 136) -> coalesced ----
    short* T = LDSu;
#pragma unroll
    for (int mi = 0; mi < 4; ++mi)
#pragma unroll
      for (int ni = 0; ni < 4; ++ni) {
        const int col = wc * 64 + ni * 16 + ll;
        const int row0 = wr * 64 + mi * 16 + lg * 4;
        const float bias = bv[bn + col];
        s16x4 t4;
#pragma unroll
        for (int r = 0; r < 4; ++r) t4[r] = f2bf(acc[mi][ni][r] + bias);
        *(s16x4*)&T[col * 136 + row0] = t4;
      }
    __syncthreads();
    const int b_ = bm >> 10;
    const int t0 = bm & 1023;
#pragma unroll
    for (int i = 0; i < 4; ++i) {
      const int c2 = tid + i * 256;            // 1024 units
      const int colL = c2 >> 3;                // 0..127
      const int rb = (c2 & 7) * 16;            // 0..112
      const s16x8 v0 = *(const s16x8*)&T[colL * 136 + rb];
      const s16x8 v1 = *(const s16x8*)&T[colL * 136 + rb + 8];
      const int gcol = bn + colL;
      const int hh = gcol >> 6, dh = gcol & 63;
      short* dst = Vw + (((size_t)b_ * Hc + hh) * DHc + dh) * Tc + t0 + rb;
      *(s16x8*)dst = v0;
      *(s16x8*)(dst + 8) = v1;
    }
    return;
  }

#pragma unroll
  for (int mi = 0; mi < 4; ++mi)
#pragma unroll
    for (int ni = 0; ni < 4; ++ni)
#pragma unroll
      for (int r = 0; r < 4; ++r) {
        const int row = bm + wr * 64 + mi * 16 + lg * 4 + r;
        const int col = bn + wc * 64 + ni * 16 + ll;
        float v = acc[mi][ni][r];
        if (z == 3) {
          // P2[h][t]=p[t]; P2[h][1024]=0; P2[h][1025+t]=p[t] (t<=1021); P2[h][2047]=0
          const int hh = col >> 6, dh = col & 63;
          const short v16 = f2bf(v);
          short* P2h = P2o + ((size_t)hh * 2048) * DHc;
          P2h[(size_t)row * DHc + dh] = v16;
          if (row <= 1021) P2h[(size_t)(1025 + row) * DHc + dh] = v16;
          if (row == 1023) P2h[(size_t)1024 * DHc + dh] = 0;
          if (row == 1022) P2h[(size_t)2047 * DHc + dh] = 0;
        } else {
          const int b_ = row >> 10, t = row & 1023, hh = col >> 6, dh = col & 63;
          const size_t o = (((size_t)b_ * Hc + hh) * Tc + t) * DHc + dh;
          if (z == 0) {
            v += bq[col];
            Quw[o] = f2bf((v + pbu[col]) * 0.125f);
            Qvw[o] = f2bf((v + pbv[col]) * 0.125f);
          } else {
            Kw[o] = f2bf(v + bk[col]);
          }
        }
      }
}

// ---------------------------------------------------------------------------
// Output projection (f32 out + bias)
// ---------------------------------------------------------------------------
__global__ __launch_bounds__(256) void wo_gemm(const short* __restrict__ A,
                                               const short* __restrict__ B,
                                               const float* __restrict__ bias,
                                               float* __restrict__ Cf) {
  __shared__ __align__(16) short As[2][4096];
  __shared__ __align__(16) short Bs[2][4096];
  f32x4 acc[4][4];
#pragma unroll
  for (int i = 0; i < 4; ++i)
#pragma unroll
    for (int j = 0; j < 4; ++j) acc[i][j] = (f32x4){0.f, 0.f, 0.f, 0.f};

  const int bm = blockIdx.x * 128, bn = blockIdx.y * 128;
  gemm_core(A, B, bm, bn, As, Bs, acc);

  const int tid = threadIdx.x;
  const int w = tid >> 6, l = tid & 63;
  const int wr = w >> 1, wc = w & 1;
  const int ll = l & 15, lg = l >> 4;
#pragma unroll
  for (int mi = 0; mi < 4; ++mi)
#pragma unroll
    for (int ni = 0; ni < 4; ++ni)
#pragma unroll
      for (int r = 0; r < 4; ++r) {
        const int row = bm + wr * 64 + mi * 16 + lg * 4 + r;
        const int col = bn + wc * 64 + ni * 16 + ll;
        Cf[(size_t)row * DIMc + col] = acc[mi][ni][r] + bias[col];
      }
}

// ---------------------------------------------------------------------------
// Flash attention -- round-8 math byte-identical (known good 198us), with ONE
// delta: pos B-frags PREFETCHED INTO REGISTERS one iteration ahead (issued
// right after the current pos passes finish consuming them), replacing the
// P2w LDS stage. Fixes round-10's exposed-latency regression while keeping
// its LDS saving (48.4 -> 29.9 KB). Both pos passes share the same frag set.
//   dq<=0 -> qv[q]  .P2[dq+1023]   (diag pass)
//   dq>=1 -> qv[q+1].P2[dq+1023]   (upper pass; P2[1024]=0 covers dq==1)
// ---------------------------------------------------------------------------
__global__ __launch_bounds__(256) void flash_attn(
    const short* __restrict__ Qu, const short* __restrict__ Qv,
    const short* __restrict__ Kg, const short* __restrict__ VTg,
    const short* __restrict__ P2, short* __restrict__ ctx) {
  __shared__ __align__(16) short L[14976];   // 29.9 KB
  short* Kt  = L;            // [key(64)][72]
  short* Vt  = L + 4608;     // [d(64)][key(64)^swz] stride 72
  short* U   = L + 9216;     // [4 waves][1440]: SPW(80x18) / P-tile(16x72)

  const int tid = threadIdx.x;
  const int w = tid >> 6, l = tid & 63;
  const int ll = l & 15, lg = l >> 4;
  // XCD swizzle (bijective: 1024 = 8 * 128)
  const int orig = blockIdx.x + (blockIdx.y << 4) + (blockIdx.z << 8);
  const int wg = (orig & 7) * 128 + (orig >> 3);
  const int qt = wg & 15, h = (wg >> 4) & 15, b = wg >> 8;
  const int q0 = qt * 64;

  const size_t bh = (size_t)b * Hc + h;
  const short* Qup = Qu + (bh * Tc + q0) * DHc;
  const short* Qvp = Qv + (bh * Tc + q0) * DHc;
  const short* Kgp = Kg + bh * Tc * DHc;
  const short* VTp = VTg + bh * DHc * Tc;
  const short* P2h = P2 + (size_t)h * 2048 * DHc;

  // ---- Q fragments straight from global (once per block) ----
  s16x8 qau[2], qav[2], qav1[2];
  {
    const short* qr  = Qup + (size_t)(w * 16 + ll) * 64;
    const short* qvr = Qvp + (size_t)(w * 16 + ll) * 64;
#pragma unroll
    for (int ks = 0; ks < 2; ++ks) {
      qau[ks]  = *(const s16x8*)(qr + ks * 32 + lg * 8);
      qav[ks]  = *(const s16x8*)(qvr + ks * 32 + lg * 8);
      // row+1 for the upper pass; qt==15 tail overread stays inside d_ws and
      // feeds only never-gathered cells (q=1023 has no dq>=1 keys).
      qav1[ks] = *(const s16x8*)(qvr + 64 + ks * 32 + lg * 8);
    }
  }

  f32x4 o[4];
#pragma unroll
  for (int cd = 0; cd < 4; ++cd) o[cd] = (f32x4){0.f, 0.f, 0.f, 0.f};
  float m_run[4], l_run[4];
#pragma unroll
  for (int r = 0; r < 4; ++r) { m_run[r] = -3.0e38f; l_run[r] = 0.f; }

  const int ci2lo = 3 - w;       // wave's first pos-frag in window space
  const int spwb = w * 1440;     // wave's U base

  // K/V prefetch (T14) + pos-frag register prefetch (single buffer: consumed
  // by the pos passes strictly before the next issue overwrites it)
  s16x8 kr[2], vr[2], pf[2][5];
  auto issue_kv = [&](int kt) {
#pragma unroll
    for (int i = 0; i < 2; ++i) {
      const int c = tid + i * 256;
      const int row = c >> 3, col8 = (c & 7) * 8;
      kr[i] = *(const s16x8*)(Kgp + (size_t)(kt * 64 + row) * 64 + col8);
      vr[i] = *(const s16x8*)(VTp + (size_t)row * Tc + kt * 64 + col8);
    }
  };
  auto issue_pos = [&](int kt) {
    const int wb = (kt - qt) * 64 + 960;   // in [0, 1920]
#pragma unroll
    for (int j = 0; j < 5; ++j) {
      const short* pr = P2h + (size_t)(wb + (ci2lo + j) * 16 + ll) * 64 + lg * 8;
      pf[0][j] = *(const s16x8*)(pr);
      pf[1][j] = *(const s16x8*)(pr + 32);
    }
  };
  issue_kv(0);
  issue_pos(0);

  for (int kt = 0; kt < 16; ++kt) {
    const int dtile = kt - qt;
    __syncthreads();  // A: all prior-iter LDS reads complete
#pragma unroll
    for (int i = 0; i < 2; ++i) {
      const int c = tid + i * 256;
      const int row = c >> 3, col8 = (c & 7) * 8;
      *(s16x8*)&Kt[row * 72 + col8] = kr[i];
      // V^T staging: same key-chunk XOR swizzle the read path expects
      *(s16x8*)&Vt[row * 72 + (col8 ^ (((row >> 3) & 3) << 3))] = vr[i];
    }
    __syncthreads();  // B: staging visible
    if (kt < 15) issue_kv(kt + 1);   // next K/V fly under this compute

    // ---- QK^T ----
    f32x4 s[4];
#pragma unroll
    for (int ci = 0; ci < 4; ++ci) s[ci] = (f32x4){0.f, 0.f, 0.f, 0.f};
#pragma unroll
    for (int ks = 0; ks < 2; ++ks) {
      s16x8 kb[4];
#pragma unroll
      for (int ci = 0; ci < 4; ++ci)
        kb[ci] = *(const s16x8*)&Kt[(ci * 16 + ll) * 72 + ks * 32 + lg * 8];
      __builtin_amdgcn_s_setprio(1);
#pragma unroll
      for (int ci = 0; ci < 4; ++ci) s[ci] = MFMA16(qau[ks], kb[ci], s[ci]);
      __builtin_amdgcn_s_setprio(0);
    }

    // ---- pos-score windows (two passes sharing prefetched frags + SPW) ----
    if (dtile <= 0) {   // diag: A = qv[q], cells dq <= 0
      f32x4 pc[5];
#pragma unroll
      for (int j = 0; j < 5; ++j) pc[j] = (f32x4){0.f, 0.f, 0.f, 0.f};
#pragma unroll
      for (int ks = 0; ks < 2; ++ks) {
        __builtin_amdgcn_s_setprio(1);
#pragma unroll
        for (int j = 0; j < 5; ++j) pc[j] = MFMA16(qav[ks], pf[ks][j], pc[j]);
        __builtin_amdgcn_s_setprio(0);
      }
#pragma unroll
      for (int j = 0; j < 5; ++j) {
        const int ba = spwb + (j * 16 + ll) * 18 + lg * 4;
        *(unsigned*)&U[ba]     = cvtpk(pc[j][0], pc[j][1]);
        *(unsigned*)&U[ba + 2] = cvtpk(pc[j][2], pc[j][3]);
      }
      asm volatile("s_waitcnt lgkmcnt(0)" ::: "memory");
#pragma unroll
      for (int ci = 0; ci < 4; ++ci)
#pragma unroll
        for (int r = 0; r < 4; ++r) {
          const int rel = ci * 16 + ll - w * 16 - lg * 4 - r;  // dq - dtile*64
          if (dtile < 0 || rel <= 0)
            s[ci][r] += bf2f(U[spwb + (rel + w * 16 + 15) * 18 + lg * 4 + r]);
        }
      asm volatile("s_waitcnt lgkmcnt(0)" ::: "memory");  // reads before reuse
    }
    if (dtile >= 0) {   // upper: A = qv[q+1], cells dq >= 1
      f32x4 pc[5];
#pragma unroll
      for (int j = 0; j < 5; ++j) pc[j] = (f32x4){0.f, 0.f, 0.f, 0.f};
#pragma unroll
      for (int ks = 0; ks < 2; ++ks) {
        __builtin_amdgcn_s_setprio(1);
#pragma unroll
        for (int j = 0; j < 5; ++j) pc[j] = MFMA16(qav1[ks], pf[ks][j], pc[j]);
        __builtin_amdgcn_s_setprio(0);
      }
#pragma unroll
      for (int j = 0; j < 5; ++j) {
        const int ba = spwb + (j * 16 + ll) * 18 + lg * 4;
        *(unsigned*)&U[ba]     = cvtpk(pc[j][0], pc[j][1]);
        *(unsigned*)&U[ba + 2] = cvtpk(pc[j][2], pc[j][3]);
      }
      asm volatile("s_waitcnt lgkmcnt(0)" ::: "memory");
#pragma unroll
      for (int ci = 0; ci < 4; ++ci)
#pragma unroll
        for (int r = 0; r < 4; ++r) {
          const int rel = ci * 16 + ll - w * 16 - lg * 4 - r;
          if (dtile > 0 || rel >= 1)
            s[ci][r] += bf2f(U[spwb + (rel + w * 16 + 15) * 18 + lg * 4 + r]);
        }
      asm volatile("s_waitcnt lgkmcnt(0)" ::: "memory");
    }
    if (kt < 15) issue_pos(kt + 1);  // pf free now; next frags fly under
                                     // softmax + PV + barrier + QK

    // ---- online softmax (rows in 16-lane groups) -- round-8 exact ----
    float fac[4];
#pragma unroll
    for (int r = 0; r < 4; ++r) {
      float mx = fmaxf(fmaxf(s[0][r], s[1][r]), fmaxf(s[2][r], s[3][r]));
      mx = fmaxf(mx, __shfl_xor(mx, 1));
      mx = fmaxf(mx, __shfl_xor(mx, 2));
      mx = fmaxf(mx, __shfl_xor(mx, 4));
      mx = fmaxf(mx, __shfl_xor(mx, 8));
      const float mnew = fmaxf(m_run[r], mx);
      const float f = __expf(m_run[r] - mnew);
      float lsum = 0.f;
#pragma unroll
      for (int ci = 0; ci < 4; ++ci) {
        const float e = __expf(s[ci][r] - mnew);
        s[ci][r] = e;
        lsum += e;
      }
      lsum += __shfl_xor(lsum, 1);
      lsum += __shfl_xor(lsum, 2);
      lsum += __shfl_xor(lsum, 4);
      lsum += __shfl_xor(lsum, 8);
      m_run[r] = mnew;
      l_run[r] = l_run[r] * f + lsum;
      fac[r] = f;
    }
#pragma unroll
    for (int cd = 0; cd < 4; ++cd)
#pragma unroll
      for (int r = 0; r < 4; ++r) o[cd][r] *= fac[r];

    // ---- P -> U (wave-private P-tile rows, stride 72; cvt_pk pairs) ----
#pragma unroll
    for (int ci = 0; ci < 4; ++ci) {
      const unsigned p01 = cvtpk(s[ci][0], s[ci][1]);
      const unsigned p23 = cvtpk(s[ci][2], s[ci][3]);
      const int base = spwb + lg * 4 * 72 + ci * 16 + ll;
      U[base]           = (short)p01;
      U[base + 72]      = (short)(p01 >> 16);
      U[base + 144]     = (short)p23;
      U[base + 216]     = (short)(p23 >> 16);
    }
    asm volatile("s_waitcnt lgkmcnt(0)" ::: "memory");

    // ---- PV ----
#pragma unroll
    for (int ks = 0; ks < 2; ++ks) {
      s16x8 pa = *(const s16x8*)&U[spwb + ll * 72 + ks * 32 + lg * 8];
      s16x8 vv[4];
#pragma unroll
      for (int cd = 0; cd < 4; ++cd) {
        const int d = cd * 16 + ll;
        const int key8 = ks * 32 + lg * 8;
        vv[cd] = *(const s16x8*)&Vt[d * 72 + (key8 ^ (((d >> 3) & 3) << 3))];
      }
      __builtin_amdgcn_s_setprio(1);
#pragma unroll
      for (int cd = 0; cd < 4; ++cd) o[cd] = MFMA16(pa, vv[cd], o[cd]);
      __builtin_amdgcn_s_setprio(0);
    }
  }

  // ---- finalize ----
#pragma unroll
  for (int r = 0; r < 4; ++r) {
    const float inv = 1.f / l_run[r];
    const int row = q0 + w * 16 + lg * 4 + r;
#pragma unroll
    for (int cd = 0; cd < 4; ++cd) {
      const int d = cd * 16 + ll;
      ctx[((size_t)b * Tc + row) * DIMc + h * DHc + d] = f2bf(o[cd][r] * inv);
    }
  }
}

// ---------------------------------------------------------------------------
extern "C" void kernel_launch(void* const* d_in, const int* in_sizes, int n_in,
                              void* d_out, int out_size, void* d_ws,
                              size_t ws_size, hipStream_t stream) {
  const float* x   = (const float*)d_in[0];
  const float* pos = (const float*)d_in[1];
  // d_in[2] = mask (all-True, unused)
  const float* Wq  = (const float*)d_in[3];
  const float* bq  = (const float*)d_in[4];
  const float* Wk  = (const float*)d_in[5];
  const float* bk  = (const float*)d_in[6];
  const float* Wv  = (const float*)d_in[7];
  const float* bv  = (const float*)d_in[8];
  const float* Wp  = (const float*)d_in[9];
  const float* Wo  = (const float*)d_in[10];
  const float* bo  = (const float*)d_in[11];
  const float* pbu = (const float*)d_in[12];
  const float* pbv = (const float*)d_in[13];
  float* out = (float*)d_out;

  char* ws = (char*)d_ws;
  const size_t MB = 1024 * 1024;
  short* xb  = (short*)(ws + 0 * MB);    // x bf16                 8 MB
  short* pb  = (short*)(ws + 8 * MB);    // pos bf16               2 MB
  short* Wqb = (short*)(ws + 10 * MB);
  short* Wkb = (short*)(ws + 12 * MB);
  short* Wvb = (short*)(ws + 14 * MB);
  short* Wpb = (short*)(ws + 16 * MB);
  short* Wob = (short*)(ws + 18 * MB);
  short* Quw = (short*)(ws + 20 * MB);   // (q+bq+pbu)/8 head-split 8 MB
  short* Qvw = (short*)(ws + 28 * MB);   // (q+bq+pbv)/8 head-split 8 MB
  short* Kw  = (short*)(ws + 36 * MB);   // [b,h,t,64]              8 MB
  short* Vw  = (short*)(ws + 44 * MB);   // V^T [b,h,64,t]          8 MB
  short* P2w_ = (short*)(ws + 52 * MB);  // P2 [h][2048][64]        4 MB
  short* Cw  = (short*)(ws + 56 * MB);   // ctx bf16 [b,t,1024]     8 MB

  const dim3 blk(256);
  hipLaunchKernelGGL(cast_f32_bf16, dim3(2048), blk, 0, stream, x, xb, 4194304);
  hipLaunchKernelGGL(cast6_f32_bf16, dim3(512, 1, 6), blk, 0, stream,
                     pos, Wq, Wk, Wv, Wp, Wo, pb, Wqb, Wkb, Wvb, Wpb, Wob);

  // Q/K/V projections + P2 table in one launch (z = 0..3)
  hipLaunchKernelGGL(proj_all, dim3(32, 8, 4), blk, 0, stream,
                     xb, pb, Wqb, Wkb, Wvb, Wpb, bq, bk, bv, pbu, pbv,
                     Quw, Qvw, Kw, Vw, P2w_);
  // fused flash attention (single launch, all batches)
  hipLaunchKernelGGL(flash_attn, dim3(16, 16, 4), blk, 0, stream,
                     Quw, Qvw, Kw, Vw, P2w_, Cw);
  // output projection (f32 out)
  hipLaunchKernelGGL(wo_gemm, dim3(32, 8), blk, 0, stream, Cw, Wob, bo, out);
}